// Round 7
// baseline (106.054 us; speedup 1.0000x reference)
//
#include <hip/hip_runtime.h>
#include <math.h>

#define NPTS 8192
#define DIMW 384
#define MB   64          // rows (points) per embed block
#define LDH  448         // embed LDS k-stride: 56 slots of 8 elems, closed under slot^7 XOR swizzle
#define KIN  416         // padded input K for inst net (385 -> 416)
#define KPOS 32          // padded input K for pos net (7 -> 32)
#define SCH  256
#define NCH  32
#define LZB  136         // dist LDS k-stride (elems)
#define EWAVES 12        // embed waves per block
#define ETHREADS (EWAVES * 64)

typedef __attribute__((ext_vector_type(8))) short bf16x8;
typedef __attribute__((ext_vector_type(4))) float f32x4;
typedef __attribute__((ext_vector_type(4))) unsigned short us4;
typedef __attribute__((ext_vector_type(8))) unsigned short us8;

// ---- bf16 weight layout in ws (ushort offsets) -----------------------------
// FRAGMENT-CONTIGUOUS for 12 waves x 2 i-frags: elem (wave, ks, i, lane, e) at
// linear idx ((((wave*NK + ks)*2 + i)*64 + lane)*8 + e), holding W^T[n][k],
//   n = wave*32 + i*16 + (lane&15), k = ks*32 + (lane>>4)*8 + e
#define SZ_HID   (384*384)
#define OFF_IIN  0
#define SZ_IIN   (384*416)
#define OFF_IHID (OFF_IIN + SZ_IIN)
#define OFF_IOUT (OFF_IHID + 5*SZ_HID)
#define OFF_PIN  (OFF_IOUT + SZ_HID)
#define SZ_PIN   (384*32)
#define OFF_PHID (OFF_PIN + SZ_PIN)
#define OFF_POUT (OFF_PHID + 3*SZ_HID)
#define WTS_USHORTS (OFF_POUT + SZ_HID)
#define WTS_BYTES   ((size_t)WTS_USHORTS * 2)        // 3,293,184
#define EMB_US      ((size_t)NPTS * DIMW)            // ushorts per variant
#define EMB_BYTES   (EMB_US * 2)                     // 6,291,456

__device__ __forceinline__ ushort f2bf(float x) {
  union { float f; unsigned u; } v; v.f = x;
  unsigned r = v.u + 0x7FFF + ((v.u >> 16) & 1);     // RNE
  return (ushort)(r >> 16);
}
__device__ __forceinline__ float bf2f(ushort u) {
  union { unsigned u; float f; } v; v.u = ((unsigned)u) << 16; return v.f;
}

// ---------------- weight convert into fragment-contiguous swizzle ------------
__global__ __launch_bounds__(256) void convert_wts_swz(
    const float* __restrict__ iWin, const float* __restrict__ iWhid,
    const float* __restrict__ iWout, const float* __restrict__ pWin,
    const float* __restrict__ pWhid, const float* __restrict__ pWout,
    ushort* __restrict__ wts) {
  const int seg = blockIdx.y;
  const float* src; ushort* dst; int Ksrc, NKl;
  if (seg == 0)      { src = iWin;  dst = wts + OFF_IIN;  Ksrc = 385; NKl = 13; }
  else if (seg <= 5) { src = iWhid + (size_t)(seg-1)*SZ_HID; dst = wts + OFF_IHID + (size_t)(seg-1)*SZ_HID; Ksrc = 384; NKl = 12; }
  else if (seg == 6) { src = iWout; dst = wts + OFF_IOUT; Ksrc = 384; NKl = 12; }
  else if (seg == 7) { src = pWin;  dst = wts + OFF_PIN;  Ksrc = 7;   NKl = 1;  }
  else if (seg <= 10){ src = pWhid + (size_t)(seg-8)*SZ_HID; dst = wts + OFF_PHID + (size_t)(seg-8)*SZ_HID; Ksrc = 384; NKl = 12; }
  else               { src = pWout; dst = wts + OFF_POUT; Ksrc = 384; NKl = 12; }
  const int t = blockIdx.x * 256 + threadIdx.x;      // one thread per 8 elems
  if (t >= NKl * 1536) return;                       // 12 waves * NK * 2 * 64
  const int lane = t & 63;
  const int frag = t >> 6;
  const int i = frag & 1;
  const int rest = frag >> 1;
  const int ks = rest % NKl;
  const int wave = rest / NKl;
  const int n  = wave * 32 + i * 16 + (lane & 15);
  const int kb = ks * 32 + (lane >> 4) * 8;
  us8 o;
#pragma unroll
  for (int e = 0; e < 8; ++e) {
    const int k = kb + e;
    o[e] = (k < Ksrc) ? f2bf(src[(size_t)k * 384 + n]) : (ushort)0;
  }
  *(us8*)&dst[(size_t)t * 8] = o;
}

// ---------------- one MFMA layer; chunk-4 double-buffered W pipeline --------
// h buffers XOR-swizzled at 16B-slot granularity: phys_slot = log_slot ^ (row&7)
template <int NK, bool STORE>
__device__ __forceinline__ void mlayer(const ushort* __restrict__ Wt,
    const ushort* __restrict__ bin, ushort* __restrict__ bout,
    int wave, int lane, int lr, int lq, int n0, f32x4 acc[2][4]) {
#pragma unroll
  for (int i = 0; i < 2; ++i)
#pragma unroll
    for (int j = 0; j < 4; ++j) acc[i][j] = (f32x4)(0.f);

  constexpr int NC = (NK + 3) / 4;
  bf16x8 w[2][4][2], h[2][4];
  const ushort* wp = Wt + (size_t)wave * NK * 1024 + lane * 8;
  const int swz = lr & 7;
  const ushort* hbase = bin + lr * LDH;

  // chunk 0 W loads (coalesced contiguous 1KB per frag)
#pragma unroll
  for (int s = 0; s < 4; ++s)
    if (s < NK)
#pragma unroll
      for (int i = 0; i < 2; ++i)
        w[0][s][i] = *(const bf16x8*)(wp + s * 1024 + i * 512);
  // k=0 h reads (swizzled)
#pragma unroll
  for (int j = 0; j < 4; ++j)
    h[0][j] = *(const bf16x8*)(hbase + j * 16 * LDH + ((lq ^ swz) << 3));

#pragma unroll
  for (int c = 0; c < NC; ++c) {
    if (c + 1 < NC) {                    // issue next W chunk before computing this one
#pragma unroll
      for (int s = 0; s < 4; ++s)
        if ((c + 1) * 4 + s < NK)
#pragma unroll
          for (int i = 0; i < 2; ++i)
            w[(c + 1) & 1][s][i] = *(const bf16x8*)(wp + (size_t)((c + 1) * 4 + s) * 1024 + i * 512);
    }
#pragma unroll
    for (int s = 0; s < 4; ++s) {
      const int ks = c * 4 + s;
      if (ks < NK) {
        if (ks + 1 < NK) {               // depth-1 h prefetch
#pragma unroll
          for (int j = 0; j < 4; ++j)
            h[(ks + 1) & 1][j] = *(const bf16x8*)(hbase + j * 16 * LDH + ((((ks + 1) * 4 + lq) ^ swz) << 3));
        }
#pragma unroll
        for (int j = 0; j < 4; ++j)
#pragma unroll
          for (int i = 0; i < 2; ++i)
            acc[i][j] = __builtin_amdgcn_mfma_f32_16x16x32_bf16(w[c & 1][s][i], h[ks & 1][j], acc[i][j], 0, 0, 0);
      }
    }
  }
  if (STORE) {
#pragma unroll
    for (int i = 0; i < 2; ++i)
#pragma unroll
      for (int j = 0; j < 4; ++j) {
        f32x4 a = acc[i][j];
        us4 o;
        o[0] = f2bf(fmaxf(a[0], 0.f));
        o[1] = f2bf(fmaxf(a[1], 0.f));
        o[2] = f2bf(fmaxf(a[2], 0.f));
        o[3] = f2bf(fmaxf(a[3], 0.f));
        const int col = n0 + i * 16 + lq * 4;
        const int slot = col >> 3;
        *(us4*)&bout[(j * 16 + lr) * LDH + (((slot ^ swz) << 3) | ((lq & 1) << 2))] = o;
      }
    __syncthreads();
  }
}

// ---------------- L2-normalize rows from accumulators, write/add bf16 emb ---
__device__ __forceinline__ void norm_store(f32x4 acc[2][4], ushort* __restrict__ embp,
    bool add, int lr, int lq, int wave, int n0, float (*wsum)[64], float* invn) {
#pragma unroll
  for (int j = 0; j < 4; ++j) {
    float s = 0.f;
#pragma unroll
    for (int i = 0; i < 2; ++i) {
      f32x4 a = acc[i][j];
      s = fmaf(a[0], a[0], s); s = fmaf(a[1], a[1], s);
      s = fmaf(a[2], a[2], s); s = fmaf(a[3], a[3], s);
    }
    s += __shfl_xor(s, 16, 64);
    s += __shfl_xor(s, 32, 64);
    if (lq == 0) wsum[wave][j * 16 + lr] = s;
  }
  __syncthreads();
  if (threadIdx.x < 64) {
    float tot = 0.f;
#pragma unroll
    for (int w = 0; w < EWAVES; ++w) tot += wsum[w][threadIdx.x];
    invn[threadIdx.x] = 1.f / (sqrtf(tot) + 1e-5f);
  }
  __syncthreads();
#pragma unroll
  for (int j = 0; j < 4; ++j) {
    const float inv = invn[j * 16 + lr];
#pragma unroll
    for (int i = 0; i < 2; ++i) {
      ushort* p = embp + (size_t)(j * 16 + lr) * DIMW + n0 + i * 16 + lq * 4;
      float o0 = acc[i][j][0] * inv, o1 = acc[i][j][1] * inv;
      float o2 = acc[i][j][2] * inv, o3 = acc[i][j][3] * inv;
      if (add) {
        us4 old = *(const us4*)p;
        o0 += bf2f(old[0]); o1 += bf2f(old[1]);
        o2 += bf2f(old[2]); o3 += bf2f(old[3]);
      }
      us4 o; o[0] = f2bf(o0); o[1] = f2bf(o1); o[2] = f2bf(o2); o[3] = f2bf(o3);
      *(us4*)p = o;
    }
  }
  __syncthreads();
}

// ---------------- fused embedding kernel (both variants via blockIdx.y) ------
__global__ __launch_bounds__(ETHREADS, 3) void embed_mfma(
    const float* __restrict__ feat_sel, const float* __restrict__ feat_org,
    const float* __restrict__ scale, const float* __restrict__ rand_u,
    const ushort* __restrict__ wts, ushort* __restrict__ emb) {
  __shared__ ushort bufA[MB * LDH];
  __shared__ ushort bufB[MB * LDH];
  __shared__ float s_lds[MB];
  __shared__ float wsum[EWAVES][64];
  __shared__ float invn[64];

  const int t = threadIdx.x;
  const int p0 = blockIdx.x * MB;
  const int var = blockIdx.y;
  ushort* embp = emb + (size_t)var * EMB_US + (size_t)p0 * DIMW;

  if (t < MB) {
    float s = scale[p0 + t];
    if (var) s += fmaxf(0.f, 2.f - s) * rand_u[0];
    s_lds[t] = s;
  }
  // stage inst input (swizzled): 64 rows x 96 us4-groups
#pragma unroll
  for (int it = 0; it < 8; ++it) {
    int idx = t + it * ETHREADS;
    int m = idx / 96, kq = idx - m * 96;
    const float4 v = *(const float4*)&feat_sel[(size_t)(p0 + m) * DIMW + kq * 4];
    us4 o; o[0] = f2bf(v.x); o[1] = f2bf(v.y); o[2] = f2bf(v.z); o[3] = f2bf(v.w);
    const int ph = (((kq >> 1) ^ (m & 7)) << 3) | ((kq & 1) << 2);
    *(us4*)&bufA[m * LDH + ph] = o;
  }
  if (t < MB) {
    us8 z = (us8)(0);
#pragma unroll
    for (int q = 48; q < 56; ++q) *(us8*)&bufA[t * LDH + q * 8] = z;
    // scale at logical col 384 (slot 48, offset 0) -> phys slot 48^(t&7) = 48+(t&7)
    bufA[t * LDH + 384 + (t & 7) * 8] = f2bf(s_lds[t]);
  }
  __syncthreads();

  const int lane = t & 63, wave = t >> 6;
  const int lr = lane & 15, lq = lane >> 4;
  const int n0 = wave * 32;
  f32x4 acc[2][4];

  mlayer<13, true >(wts + OFF_IIN,             bufA, bufB, wave, lane, lr, lq, n0, acc);
  mlayer<12, true >(wts + OFF_IHID + 0*SZ_HID, bufB, bufA, wave, lane, lr, lq, n0, acc);
  mlayer<12, true >(wts + OFF_IHID + 1*SZ_HID, bufA, bufB, wave, lane, lr, lq, n0, acc);
  mlayer<12, true >(wts + OFF_IHID + 2*SZ_HID, bufB, bufA, wave, lane, lr, lq, n0, acc);
  mlayer<12, true >(wts + OFF_IHID + 3*SZ_HID, bufA, bufB, wave, lane, lr, lq, n0, acc);
  mlayer<12, true >(wts + OFF_IHID + 4*SZ_HID, bufB, bufA, wave, lane, lr, lq, n0, acc);
  mlayer<12, false>(wts + OFF_IOUT,            bufA, bufB, wave, lane, lr, lq, n0, acc);
  norm_store(acc, embp, false, lr, lq, wave, n0, wsum, invn);

  if (t < MB) {
    const float* fo = feat_org + (size_t)(p0 + t) * 6;
    us8 b0;
#pragma unroll
    for (int k = 0; k < 6; ++k) b0[k] = f2bf(fo[k]);
    b0[6] = f2bf(s_lds[t]);
    b0[7] = 0;
    us8 z = (us8)(0);
    const int e = t & 7;
    *(us8*)&bufA[t * LDH + ((0 ^ e) << 3)] = b0;
    *(us8*)&bufA[t * LDH + ((1 ^ e) << 3)] = z;
    *(us8*)&bufA[t * LDH + ((2 ^ e) << 3)] = z;
    *(us8*)&bufA[t * LDH + ((3 ^ e) << 3)] = z;
  }
  __syncthreads();

  mlayer<1,  true >(wts + OFF_PIN,             bufA, bufB, wave, lane, lr, lq, n0, acc);
  mlayer<12, true >(wts + OFF_PHID + 0*SZ_HID, bufB, bufA, wave, lane, lr, lq, n0, acc);
  mlayer<12, true >(wts + OFF_PHID + 1*SZ_HID, bufA, bufB, wave, lane, lr, lq, n0, acc);
  mlayer<12, true >(wts + OFF_PHID + 2*SZ_HID, bufB, bufA, wave, lane, lr, lq, n0, acc);
  mlayer<12, false>(wts + OFF_POUT,            bufA, bufB, wave, lane, lr, lq, n0, acc);
  norm_store(acc, embp, true, lr, lq, wave, n0, wsum, invn);
}

// ---------------- MFMA gram dist + masked partial sums ----------------------
// grid (chunk, half, variant); block 512 = 8 waves (2 wa x 4 wb), 64x64 tiles
__global__ __launch_bounds__(512) void dist_mfma(
    const ushort* __restrict__ emb, const int* __restrict__ mask_id,
    float* __restrict__ part) {
  __shared__ ushort zb[SCH * LZB];
  __shared__ float sqv[SCH];
  __shared__ int labv[SCH];
  __shared__ float scratch[8];

  const int c = blockIdx.x, hh = blockIdx.y, v = blockIdx.z;
  const int t = threadIdx.x;
  const ushort* embc = emb + (size_t)v * EMB_US + (size_t)c * SCH * DIMW;

  if (t < SCH) labv[t] = mask_id[c * SCH + t];

  const int lane = t & 63, wave = t >> 6;
  const int lr = lane & 15, lq = lane >> 4;
  const int wa = wave >> 2, wb = wave & 3;

  f32x4 acc[4][4];
#pragma unroll
  for (int i = 0; i < 4; ++i)
#pragma unroll
    for (int j = 0; j < 4; ++j) acc[i][j] = (f32x4)(0.f);

  const int sr = t >> 1, sh = (t & 1) * 64;   // staging: row, k-half (elems)
  float sq = 0.f;

  for (int kc = 0; kc < 3; ++kc) {
    __syncthreads();
    const ushort* zrow = embc + (size_t)sr * DIMW + kc * 128 + sh;
    ushort* zd = zb + sr * LZB + sh;
#pragma unroll
    for (int q = 0; q < 8; ++q) {
      us8 x = *(const us8*)&zrow[q * 8];
      *(us8*)&zd[q * 8] = x;
#pragma unroll
      for (int e = 0; e < 8; ++e) { float f = bf2f(x[e]); sq = fmaf(f, f, sq); }
    }
    __syncthreads();
    const ushort* ap = zb + (hh * 128 + wa * 64 + lr) * LZB + lq * 8;
    const ushort* bp = zb + (wb * 64 + lr) * LZB + lq * 8;
#pragma unroll
    for (int ks = 0; ks < 4; ++ks) {
      bf16x8 af[4], bfr[4];
#pragma unroll
      for (int i = 0; i < 4; ++i) af[i] = *(const bf16x8*)(ap + i * 16 * LZB + ks * 32);
#pragma unroll
      for (int j = 0; j < 4; ++j) bfr[j] = *(const bf16x8*)(bp + j * 16 * LZB + ks * 32);
#pragma unroll
      for (int j = 0; j < 4; ++j)
#pragma unroll
        for (int i = 0; i < 4; ++i)
          acc[i][j] = __builtin_amdgcn_mfma_f32_16x16x32_bf16(af[i], bfr[j], acc[i][j], 0, 0, 0);
    }
  }
  sq += __shfl_xor(sq, 1, 64);
  if (!(t & 1)) sqv[sr] = sq;
  __syncthreads();

  float s_pos = 0.f, s_neg = 0.f, c_pos = 0.f, c_neg = 0.f, c_blk = 0.f;
#pragma unroll
  for (int i = 0; i < 4; ++i) {
    const int ib = hh * 128 + wa * 64 + i * 16 + lq * 4;
#pragma unroll
    for (int j = 0; j < 4; ++j) {
      const int jG = wb * 64 + j * 16 + lr;
      const int lj = labv[jG];
      const float sqj = sqv[jG];
#pragma unroll
      for (int vv = 0; vv < 4; ++vv) {
        const int iG = ib + vv;
        const int li = labv[iG];
        if (li != -1 && lj != -1 && iG <= jG) {
          c_blk += 1.f;
          if (iG < jG) {
            float d2 = sqv[iG] + sqj - 2.f * acc[i][j][vv];
            float d = sqrtf(fmaxf(d2, 1e-12f));
            if (li == lj) { s_pos += d; c_pos += 1.f; }
            else          { s_neg += fmaxf(1.f - d, 0.f); c_neg += 1.f; }
          }
        }
      }
    }
  }
  // deterministic block reduce (512 threads)
  float vals[5] = { s_pos, s_neg, c_pos, c_neg, c_blk };
  float res[5];
#pragma unroll
  for (int r = 0; r < 5; ++r) {
    float x = vals[r];
#pragma unroll
    for (int o = 32; o > 0; o >>= 1) x += __shfl_xor(x, o, 64);
    __syncthreads();
    if ((t & 63) == 0) scratch[t >> 6] = x;
    __syncthreads();
    float s = 0.f;
#pragma unroll
    for (int w = 0; w < 8; ++w) s += scratch[w];
    res[r] = s;
  }
  if (t == 0) {
    float* pb = part + (size_t)((v * 2 + hh) * NCH + c) * 8;
    pb[0] = res[0]; pb[1] = res[1]; pb[2] = res[2]; pb[3] = res[3]; pb[4] = res[4];
  }
}

// ---------------- combine 128 partial slots into the scalar loss ------------
__global__ __launch_bounds__(128) void final_kernel(
    const float* __restrict__ part, float* __restrict__ out) {
  __shared__ float scratch[2];
  const int t = threadIdx.x;
  const float* pb = part + (size_t)t * 8;
  const bool v0 = t < 64;
  float sp1 = v0 ? pb[0] : 0.f;
  float sp2 = v0 ? 0.f : pb[0];
  float sn  = v0 ? pb[1] : 0.f;
  float cp  = v0 ? pb[2] : 0.f;
  float cn  = v0 ? pb[3] : 0.f;
  float cb  = v0 ? pb[4] : 0.f;
  float vals[6] = { sp1, sp2, sn, cp, cn, cb };
  float res[6];
#pragma unroll
  for (int r = 0; r < 6; ++r) {
    float x = vals[r];
#pragma unroll
    for (int o = 32; o > 0; o >>= 1) x += __shfl_xor(x, o, 64);
    __syncthreads();
    if ((t & 63) == 0) scratch[t >> 6] = x;
    __syncthreads();
    res[r] = scratch[0] + scratch[1];
  }
  if (t == 0) {
    float l1 = res[0] / fmaxf(res[3], 1.f);
    float l2 = res[1] / fmaxf(res[3], 1.f);
    float l3 = res[2] / fmaxf(res[4], 1.f);
    out[0] = (l1 + l2) * (res[3] / res[5]) + l3 * (res[4] / res[5]);
  }
}

extern "C" void kernel_launch(void* const* d_in, const int* in_sizes, int n_in,
                              void* d_out, int out_size, void* d_ws, size_t ws_size,
                              hipStream_t stream) {
  const float* feat_sel = (const float*)d_in[0];
  const float* feat_org = (const float*)d_in[1];
  const float* scale    = (const float*)d_in[2];
  const int*   mask_id  = (const int*)d_in[3];
  const float* rand_u   = (const float*)d_in[4];
  const float* iWin  = (const float*)d_in[6];
  const float* iWhid = (const float*)d_in[7];
  const float* iWout = (const float*)d_in[8];
  const float* pWin  = (const float*)d_in[9];
  const float* pWhid = (const float*)d_in[10];
  const float* pWout = (const float*)d_in[11];

  ushort* wts = (ushort*)d_ws;
  ushort* emb = (ushort*)((char*)d_ws + WTS_BYTES);          // 2 variants bf16
  float*  part = (float*)((char*)d_ws + WTS_BYTES + 2 * EMB_BYTES);

  dim3 gC(78, 12);    // 78*256 threads covers max layer (NK=13 -> 19968)
  convert_wts_swz<<<gC, 256, 0, stream>>>(iWin, iWhid, iWout, pWin, pWhid, pWout, wts);

  dim3 gE(NPTS / MB, 2);
  embed_mfma<<<gE, ETHREADS, 0, stream>>>(feat_sel, feat_org, scale, rand_u, wts, emb);

  dim3 gD(NCH, 2, 2);
  dist_mfma<<<gD, 512, 0, stream>>>(emb, mask_id, part);

  final_kernel<<<1, 128, 0, stream>>>(part, (float*)d_out);
}

// Round 9
// 103.359 us; speedup vs baseline: 1.0261x; 1.0261x over previous
//
#include <hip/hip_runtime.h>
#include <math.h>

#define NPTS 8192
#define DIMW 384
#define MB   64          // rows (points) per embed block
#define LDH  448         // embed LDS k-stride: 56 slots of 8 elems, closed under slot^7 XOR swizzle
#define KIN  416         // padded input K for inst net (385 -> 416)
#define KPOS 32          // padded input K for pos net (7 -> 32)
#define SCH  256
#define NCH  32
#define LZB  136         // dist LDS k-stride (elems)
#define EWAVES 12        // embed waves per block
#define ETHREADS (EWAVES * 64)

typedef __attribute__((ext_vector_type(8))) short bf16x8;
typedef __attribute__((ext_vector_type(4))) float f32x4;
typedef __attribute__((ext_vector_type(4))) unsigned short us4;
typedef __attribute__((ext_vector_type(8))) unsigned short us8;

// async W-fragment load the compiler cannot sink; pair with explicit
// s_waitcnt vmcnt(0) + sched_barrier(0) before first use (rule #18).
#define WLOAD(dst, ptr) \
  asm volatile("global_load_dwordx4 %0, %1, off" : "=v"(dst) : "v"(ptr) : "memory")
#define WWAIT() do { \
  asm volatile("s_waitcnt vmcnt(0)" ::: "memory"); \
  __builtin_amdgcn_sched_barrier(0); } while (0)

// ---- bf16 weight layout in ws (ushort offsets) -----------------------------
// FRAGMENT-CONTIGUOUS for 12 waves x 2 i-frags: elem (wave, ks, i, lane, e) at
// linear idx ((((wave*NK + ks)*2 + i)*64 + lane)*8 + e), holding W^T[n][k],
//   n = wave*32 + i*16 + (lane&15), k = ks*32 + (lane>>4)*8 + e
#define SZ_HID   (384*384)
#define OFF_IIN  0
#define SZ_IIN   (384*416)
#define OFF_IHID (OFF_IIN + SZ_IIN)
#define OFF_IOUT (OFF_IHID + 5*SZ_HID)
#define OFF_PIN  (OFF_IOUT + SZ_HID)
#define SZ_PIN   (384*32)
#define OFF_PHID (OFF_PIN + SZ_PIN)
#define OFF_POUT (OFF_PHID + 3*SZ_HID)
#define WTS_USHORTS (OFF_POUT + SZ_HID)
#define WTS_BYTES   ((size_t)WTS_USHORTS * 2)        // 3,293,184
#define EMB_US      ((size_t)NPTS * DIMW)            // ushorts per variant
#define EMB_BYTES   (EMB_US * 2)                     // 6,291,456

__device__ __forceinline__ ushort f2bf(float x) {
  union { float f; unsigned u; } v; v.f = x;
  unsigned r = v.u + 0x7FFF + ((v.u >> 16) & 1);     // RNE
  return (ushort)(r >> 16);
}
__device__ __forceinline__ float bf2f(ushort u) {
  union { unsigned u; float f; } v; v.u = ((unsigned)u) << 16; return v.f;
}

// ---------------- weight convert into fragment-contiguous swizzle ------------
__global__ __launch_bounds__(256) void convert_wts_swz(
    const float* __restrict__ iWin, const float* __restrict__ iWhid,
    const float* __restrict__ iWout, const float* __restrict__ pWin,
    const float* __restrict__ pWhid, const float* __restrict__ pWout,
    ushort* __restrict__ wts) {
  const int seg = blockIdx.y;
  const float* src; ushort* dst; int Ksrc, NKl;
  if (seg == 0)      { src = iWin;  dst = wts + OFF_IIN;  Ksrc = 385; NKl = 13; }
  else if (seg <= 5) { src = iWhid + (size_t)(seg-1)*SZ_HID; dst = wts + OFF_IHID + (size_t)(seg-1)*SZ_HID; Ksrc = 384; NKl = 12; }
  else if (seg == 6) { src = iWout; dst = wts + OFF_IOUT; Ksrc = 384; NKl = 12; }
  else if (seg == 7) { src = pWin;  dst = wts + OFF_PIN;  Ksrc = 7;   NKl = 1;  }
  else if (seg <= 10){ src = pWhid + (size_t)(seg-8)*SZ_HID; dst = wts + OFF_PHID + (size_t)(seg-8)*SZ_HID; Ksrc = 384; NKl = 12; }
  else               { src = pWout; dst = wts + OFF_POUT; Ksrc = 384; NKl = 12; }
  const int t = blockIdx.x * 256 + threadIdx.x;      // one thread per 8 elems
  if (t >= NKl * 1536) return;                       // 12 waves * NK * 2 * 64
  const int lane = t & 63;
  const int frag = t >> 6;
  const int i = frag & 1;
  const int rest = frag >> 1;
  const int ks = rest % NKl;
  const int wave = rest / NKl;
  const int n  = wave * 32 + i * 16 + (lane & 15);
  const int kb = ks * 32 + (lane >> 4) * 8;
  us8 o;
#pragma unroll
  for (int e = 0; e < 8; ++e) {
    const int k = kb + e;
    o[e] = (k < Ksrc) ? f2bf(src[(size_t)k * 384 + n]) : (ushort)0;
  }
  *(us8*)&dst[(size_t)t * 8] = o;
}

// ---------------- one MFMA layer; asm-pinned chunk-4 W double-buffer --------
// h buffers XOR-swizzled at 16B-slot granularity: phys_slot = log_slot ^ (row&7)
template <int NK, bool STORE>
__device__ __forceinline__ void mlayer(const ushort* __restrict__ Wt,
    const ushort* __restrict__ bin, ushort* __restrict__ bout,
    int wave, int lane, int lr, int lq, int n0, f32x4 acc[2][4]) {
#pragma unroll
  for (int i = 0; i < 2; ++i)
#pragma unroll
    for (int j = 0; j < 4; ++j) acc[i][j] = (f32x4)(0.f);

  constexpr int NC = (NK + 3) / 4;
  bf16x8 w[2][4][2], h[2][4];
  const ushort* wp = Wt + (size_t)wave * NK * 1024 + lane * 8;
  const int swz = lr & 7;
  const ushort* hbase = bin + lr * LDH;

  // prologue: issue chunk-0 W loads (coalesced contiguous 1KB per frag)
#pragma unroll
  for (int s = 0; s < 4; ++s)
    if (s < NK) {
      WLOAD(w[0][s][0], wp + s * 1024);
      WLOAD(w[0][s][1], wp + s * 1024 + 512);
    }
  // k=0 h reads (swizzled)
#pragma unroll
  for (int j = 0; j < 4; ++j)
    h[0][j] = *(const bf16x8*)(hbase + j * 16 * LDH + ((lq ^ swz) << 3));
  WWAIT();

#pragma unroll
  for (int c = 0; c < NC; ++c) {
    if (c + 1 < NC) {                    // issue next W chunk before this one's MFMAs
#pragma unroll
      for (int s = 0; s < 4; ++s)
        if ((c + 1) * 4 + s < NK) {
          WLOAD(w[(c + 1) & 1][s][0], wp + (size_t)((c + 1) * 4 + s) * 1024);
          WLOAD(w[(c + 1) & 1][s][1], wp + (size_t)((c + 1) * 4 + s) * 1024 + 512);
        }
      __builtin_amdgcn_sched_barrier(0); // pin: loads issued before compute below
    }
#pragma unroll
    for (int s = 0; s < 4; ++s) {
      const int ks = c * 4 + s;
      if (ks < NK) {
        if (ks + 1 < NK) {               // depth-1 h prefetch
#pragma unroll
          for (int j = 0; j < 4; ++j)
            h[(ks + 1) & 1][j] = *(const bf16x8*)(hbase + j * 16 * LDH + ((((ks + 1) * 4 + lq) ^ swz) << 3));
        }
#pragma unroll
        for (int j = 0; j < 4; ++j)
#pragma unroll
          for (int i = 0; i < 2; ++i)
            acc[i][j] = __builtin_amdgcn_mfma_f32_16x16x32_bf16(w[c & 1][s][i], h[ks & 1][j], acc[i][j], 0, 0, 0);
      }
    }
    if (c + 1 < NC) WWAIT();             // chunk c+1 regs ready before next iter uses them
  }
  if (STORE) {
#pragma unroll
    for (int i = 0; i < 2; ++i)
#pragma unroll
      for (int j = 0; j < 4; ++j) {
        f32x4 a = acc[i][j];
        us4 o;
        o[0] = f2bf(fmaxf(a[0], 0.f));
        o[1] = f2bf(fmaxf(a[1], 0.f));
        o[2] = f2bf(fmaxf(a[2], 0.f));
        o[3] = f2bf(fmaxf(a[3], 0.f));
        const int col = n0 + i * 16 + lq * 4;
        const int slot = col >> 3;
        *(us4*)&bout[(j * 16 + lr) * LDH + (((slot ^ swz) << 3) | ((lq & 1) << 2))] = o;
      }
    __syncthreads();
  }
}

// ---------------- L2-normalize rows from accumulators, write/add bf16 emb ---
__device__ __forceinline__ void norm_store(f32x4 acc[2][4], ushort* __restrict__ embp,
    bool add, int lr, int lq, int wave, int n0, float (*wsum)[64], float* invn) {
#pragma unroll
  for (int j = 0; j < 4; ++j) {
    float s = 0.f;
#pragma unroll
    for (int i = 0; i < 2; ++i) {
      f32x4 a = acc[i][j];
      s = fmaf(a[0], a[0], s); s = fmaf(a[1], a[1], s);
      s = fmaf(a[2], a[2], s); s = fmaf(a[3], a[3], s);
    }
    s += __shfl_xor(s, 16, 64);
    s += __shfl_xor(s, 32, 64);
    if (lq == 0) wsum[wave][j * 16 + lr] = s;
  }
  __syncthreads();
  if (threadIdx.x < 64) {
    float tot = 0.f;
#pragma unroll
    for (int w = 0; w < EWAVES; ++w) tot += wsum[w][threadIdx.x];
    invn[threadIdx.x] = 1.f / (sqrtf(tot) + 1e-5f);
  }
  __syncthreads();
#pragma unroll
  for (int j = 0; j < 4; ++j) {
    const float inv = invn[j * 16 + lr];
#pragma unroll
    for (int i = 0; i < 2; ++i) {
      ushort* p = embp + (size_t)(j * 16 + lr) * DIMW + n0 + i * 16 + lq * 4;
      float o0 = acc[i][j][0] * inv, o1 = acc[i][j][1] * inv;
      float o2 = acc[i][j][2] * inv, o3 = acc[i][j][3] * inv;
      if (add) {
        us4 old = *(const us4*)p;
        o0 += bf2f(old[0]); o1 += bf2f(old[1]);
        o2 += bf2f(old[2]); o3 += bf2f(old[3]);
      }
      us4 o; o[0] = f2bf(o0); o[1] = f2bf(o1); o[2] = f2bf(o2); o[3] = f2bf(o3);
      *(us4*)p = o;
    }
  }
  __syncthreads();
}

// ---------------- fused embedding kernel (both variants via blockIdx.y) ------
__global__ __launch_bounds__(ETHREADS, 3) void embed_mfma(
    const float* __restrict__ feat_sel, const float* __restrict__ feat_org,
    const float* __restrict__ scale, const float* __restrict__ rand_u,
    const ushort* __restrict__ wts, ushort* __restrict__ emb) {
  __shared__ ushort bufA[MB * LDH];
  __shared__ ushort bufB[MB * LDH];
  __shared__ float s_lds[MB];
  __shared__ float wsum[EWAVES][64];
  __shared__ float invn[64];

  const int t = threadIdx.x;
  const int p0 = blockIdx.x * MB;
  const int var = blockIdx.y;
  ushort* embp = emb + (size_t)var * EMB_US + (size_t)p0 * DIMW;

  if (t < MB) {
    float s = scale[p0 + t];
    if (var) s += fmaxf(0.f, 2.f - s) * rand_u[0];
    s_lds[t] = s;
  }
  // stage inst input (swizzled): 64 rows x 96 us4-groups
#pragma unroll
  for (int it = 0; it < 8; ++it) {
    int idx = t + it * ETHREADS;
    int m = idx / 96, kq = idx - m * 96;
    const float4 v = *(const float4*)&feat_sel[(size_t)(p0 + m) * DIMW + kq * 4];
    us4 o; o[0] = f2bf(v.x); o[1] = f2bf(v.y); o[2] = f2bf(v.z); o[3] = f2bf(v.w);
    const int ph = (((kq >> 1) ^ (m & 7)) << 3) | ((kq & 1) << 2);
    *(us4*)&bufA[m * LDH + ph] = o;
  }
  if (t < MB) {
    us8 z = (us8)(0);
#pragma unroll
    for (int q = 48; q < 56; ++q) *(us8*)&bufA[t * LDH + q * 8] = z;
    // scale at logical col 384 (slot 48, offset 0) -> phys slot 48^(t&7) = 48+(t&7)
    bufA[t * LDH + 384 + (t & 7) * 8] = f2bf(s_lds[t]);
  }
  __syncthreads();

  const int lane = t & 63, wave = t >> 6;
  const int lr = lane & 15, lq = lane >> 4;
  const int n0 = wave * 32;
  f32x4 acc[2][4];

  mlayer<13, true >(wts + OFF_IIN,             bufA, bufB, wave, lane, lr, lq, n0, acc);
  mlayer<12, true >(wts + OFF_IHID + 0*SZ_HID, bufB, bufA, wave, lane, lr, lq, n0, acc);
  mlayer<12, true >(wts + OFF_IHID + 1*SZ_HID, bufA, bufB, wave, lane, lr, lq, n0, acc);
  mlayer<12, true >(wts + OFF_IHID + 2*SZ_HID, bufB, bufA, wave, lane, lr, lq, n0, acc);
  mlayer<12, true >(wts + OFF_IHID + 3*SZ_HID, bufA, bufB, wave, lane, lr, lq, n0, acc);
  mlayer<12, true >(wts + OFF_IHID + 4*SZ_HID, bufB, bufA, wave, lane, lr, lq, n0, acc);
  mlayer<12, false>(wts + OFF_IOUT,            bufA, bufB, wave, lane, lr, lq, n0, acc);
  norm_store(acc, embp, false, lr, lq, wave, n0, wsum, invn);

  if (t < MB) {
    const float* fo = feat_org + (size_t)(p0 + t) * 6;
    us8 b0;
#pragma unroll
    for (int k = 0; k < 6; ++k) b0[k] = f2bf(fo[k]);
    b0[6] = f2bf(s_lds[t]);
    b0[7] = 0;
    us8 z = (us8)(0);
    const int e = t & 7;
    *(us8*)&bufA[t * LDH + ((0 ^ e) << 3)] = b0;
    *(us8*)&bufA[t * LDH + ((1 ^ e) << 3)] = z;
    *(us8*)&bufA[t * LDH + ((2 ^ e) << 3)] = z;
    *(us8*)&bufA[t * LDH + ((3 ^ e) << 3)] = z;
  }
  __syncthreads();

  mlayer<1,  true >(wts + OFF_PIN,             bufA, bufB, wave, lane, lr, lq, n0, acc);
  mlayer<12, true >(wts + OFF_PHID + 0*SZ_HID, bufB, bufA, wave, lane, lr, lq, n0, acc);
  mlayer<12, true >(wts + OFF_PHID + 1*SZ_HID, bufA, bufB, wave, lane, lr, lq, n0, acc);
  mlayer<12, true >(wts + OFF_PHID + 2*SZ_HID, bufB, bufA, wave, lane, lr, lq, n0, acc);
  mlayer<12, false>(wts + OFF_POUT,            bufA, bufB, wave, lane, lr, lq, n0, acc);
  norm_store(acc, embp, true, lr, lq, wave, n0, wsum, invn);
}

// ---------------- MFMA gram dist + masked partial sums ----------------------
// grid (chunk, half, variant); block 512 = 8 waves (2 wa x 4 wb), 64x64 tiles
__global__ __launch_bounds__(512) void dist_mfma(
    const ushort* __restrict__ emb, const int* __restrict__ mask_id,
    float* __restrict__ part) {
  __shared__ ushort zb[SCH * LZB];
  __shared__ float sqv[SCH];
  __shared__ int labv[SCH];
  __shared__ float scratch[8];

  const int c = blockIdx.x, hh = blockIdx.y, v = blockIdx.z;
  const int t = threadIdx.x;
  const ushort* embc = emb + (size_t)v * EMB_US + (size_t)c * SCH * DIMW;

  if (t < SCH) labv[t] = mask_id[c * SCH + t];

  const int lane = t & 63, wave = t >> 6;
  const int lr = lane & 15, lq = lane >> 4;
  const int wa = wave >> 2, wb = wave & 3;

  f32x4 acc[4][4];
#pragma unroll
  for (int i = 0; i < 4; ++i)
#pragma unroll
    for (int j = 0; j < 4; ++j) acc[i][j] = (f32x4)(0.f);

  const int sr = t >> 1, sh = (t & 1) * 64;   // staging: row, k-half (elems)
  float sq = 0.f;

  for (int kc = 0; kc < 3; ++kc) {
    __syncthreads();
    const ushort* zrow = embc + (size_t)sr * DIMW + kc * 128 + sh;
    ushort* zd = zb + sr * LZB + sh;
#pragma unroll
    for (int q = 0; q < 8; ++q) {
      us8 x = *(const us8*)&zrow[q * 8];
      *(us8*)&zd[q * 8] = x;
#pragma unroll
      for (int e = 0; e < 8; ++e) { float f = bf2f(x[e]); sq = fmaf(f, f, sq); }
    }
    __syncthreads();
    const ushort* ap = zb + (hh * 128 + wa * 64 + lr) * LZB + lq * 8;
    const ushort* bp = zb + (wb * 64 + lr) * LZB + lq * 8;
#pragma unroll
    for (int ks = 0; ks < 4; ++ks) {
      bf16x8 af[4], bfr[4];
#pragma unroll
      for (int i = 0; i < 4; ++i) af[i] = *(const bf16x8*)(ap + i * 16 * LZB + ks * 32);
#pragma unroll
      for (int j = 0; j < 4; ++j) bfr[j] = *(const bf16x8*)(bp + j * 16 * LZB + ks * 32);
#pragma unroll
      for (int j = 0; j < 4; ++j)
#pragma unroll
        for (int i = 0; i < 4; ++i)
          acc[i][j] = __builtin_amdgcn_mfma_f32_16x16x32_bf16(af[i], bfr[j], acc[i][j], 0, 0, 0);
    }
  }
  sq += __shfl_xor(sq, 1, 64);
  if (!(t & 1)) sqv[sr] = sq;
  __syncthreads();

  float s_pos = 0.f, s_neg = 0.f, c_pos = 0.f, c_neg = 0.f, c_blk = 0.f;
#pragma unroll
  for (int i = 0; i < 4; ++i) {
    const int ib = hh * 128 + wa * 64 + i * 16 + lq * 4;
#pragma unroll
    for (int j = 0; j < 4; ++j) {
      const int jG = wb * 64 + j * 16 + lr;
      const int lj = labv[jG];
      const float sqj = sqv[jG];
#pragma unroll
      for (int vv = 0; vv < 4; ++vv) {
        const int iG = ib + vv;
        const int li = labv[iG];
        if (li != -1 && lj != -1 && iG <= jG) {
          c_blk += 1.f;
          if (iG < jG) {
            float d2 = sqv[iG] + sqj - 2.f * acc[i][j][vv];
            float d = sqrtf(fmaxf(d2, 1e-12f));
            if (li == lj) { s_pos += d; c_pos += 1.f; }
            else          { s_neg += fmaxf(1.f - d, 0.f); c_neg += 1.f; }
          }
        }
      }
    }
  }
  // deterministic block reduce (512 threads)
  float vals[5] = { s_pos, s_neg, c_pos, c_neg, c_blk };
  float res[5];
#pragma unroll
  for (int r = 0; r < 5; ++r) {
    float x = vals[r];
#pragma unroll
    for (int o = 32; o > 0; o >>= 1) x += __shfl_xor(x, o, 64);
    __syncthreads();
    if ((t & 63) == 0) scratch[t >> 6] = x;
    __syncthreads();
    float s = 0.f;
#pragma unroll
    for (int w = 0; w < 8; ++w) s += scratch[w];
    res[r] = s;
  }
  if (t == 0) {
    float* pb = part + (size_t)((v * 2 + hh) * NCH + c) * 8;
    pb[0] = res[0]; pb[1] = res[1]; pb[2] = res[2]; pb[3] = res[3]; pb[4] = res[4];
  }
}

// ---------------- combine 128 partial slots into the scalar loss ------------
__global__ __launch_bounds__(128) void final_kernel(
    const float* __restrict__ part, float* __restrict__ out) {
  __shared__ float scratch[2];
  const int t = threadIdx.x;
  const float* pb = part + (size_t)t * 8;
  const bool v0 = t < 64;
  float sp1 = v0 ? pb[0] : 0.f;
  float sp2 = v0 ? 0.f : pb[0];
  float sn  = v0 ? pb[1] : 0.f;
  float cp  = v0 ? pb[2] : 0.f;
  float cn  = v0 ? pb[3] : 0.f;
  float cb  = v0 ? pb[4] : 0.f;
  float vals[6] = { sp1, sp2, sn, cp, cn, cb };
  float res[6];
#pragma unroll
  for (int r = 0; r < 6; ++r) {
    float x = vals[r];
#pragma unroll
    for (int o = 32; o > 0; o >>= 1) x += __shfl_xor(x, o, 64);
    __syncthreads();
    if ((t & 63) == 0) scratch[t >> 6] = x;
    __syncthreads();
    res[r] = scratch[0] + scratch[1];
  }
  if (t == 0) {
    float l1 = res[0] / fmaxf(res[3], 1.f);
    float l2 = res[1] / fmaxf(res[3], 1.f);
    float l3 = res[2] / fmaxf(res[4], 1.f);
    out[0] = (l1 + l2) * (res[3] / res[5]) + l3 * (res[4] / res[5]);
  }
}

extern "C" void kernel_launch(void* const* d_in, const int* in_sizes, int n_in,
                              void* d_out, int out_size, void* d_ws, size_t ws_size,
                              hipStream_t stream) {
  const float* feat_sel = (const float*)d_in[0];
  const float* feat_org = (const float*)d_in[1];
  const float* scale    = (const float*)d_in[2];
  const int*   mask_id  = (const int*)d_in[3];
  const float* rand_u   = (const float*)d_in[4];
  const float* iWin  = (const float*)d_in[6];
  const float* iWhid = (const float*)d_in[7];
  const float* iWout = (const float*)d_in[8];
  const float* pWin  = (const float*)d_in[9];
  const float* pWhid = (const float*)d_in[10];
  const float* pWout = (const float*)d_in[11];

  ushort* wts = (ushort*)d_ws;
  ushort* emb = (ushort*)((char*)d_ws + WTS_BYTES);          // 2 variants bf16
  float*  part = (float*)((char*)d_ws + WTS_BYTES + 2 * EMB_BYTES);

  dim3 gC(78, 12);    // 78*256 threads covers max layer (NK=13 -> 19968)
  convert_wts_swz<<<gC, 256, 0, stream>>>(iWin, iWhid, iWout, pWin, pWhid, pWout, wts);

  dim3 gE(NPTS / MB, 2);
  embed_mfma<<<gE, ETHREADS, 0, stream>>>(feat_sel, feat_org, scale, rand_u, wts, emb);

  dim3 gD(NCH, 2, 2);
  dist_mfma<<<gD, 512, 0, stream>>>(emb, mask_id, part);

  final_kernel<<<1, 128, 0, stream>>>(part, (float*)d_out);
}